// Round 9
// baseline (57.241 us; speedup 1.0000x reference)
//
#include <hip/hip_runtime.h>
#include <hip/hip_bf16.h>

#define N_NODES 100000
#define T_DIM 64
#define D_DIM 128
#define M_MATS 8
#define CROSS_PRUNE 0.1f
#define NCHUNK 1563     // ceil(100000/64)
#define GRID 521        // 1563 = 3 * 521 exactly
#define CPB 3           // chunks per block

typedef __attribute__((ext_vector_type(8))) short bf16x8;    // MFMA A/B fragment
typedef __attribute__((ext_vector_type(4))) float f32x4;     // MFMA accumulator
typedef __attribute__((ext_vector_type(8))) unsigned short ushort8;

// RNE 3-level split via native casts. r1 = v - bf(v), r2 = r1 - bf(r1) exact (Sterbenz).
__device__ __forceinline__ void split3(float v, unsigned short& h,
                                       unsigned short& m, unsigned short& l) {
    __hip_bfloat16 bh = __float2bfloat16(v);
    float fh = __bfloat162float(bh);
    float r1 = v - fh;
    __hip_bfloat16 bm = __float2bfloat16(r1);
    float fm = __bfloat162float(bm);
    float r2 = r1 - fm;
    __hip_bfloat16 bl = __float2bfloat16(r2);
    h = __builtin_bit_cast(unsigned short, bh);
    m = __builtin_bit_cast(unsigned short, bm);
    l = __builtin_bit_cast(unsigned short, bl);
}

// Fused kernel: 521 blocks x 256 thr (4 waves); each block does exactly 3 chunks
// of 64 n, software-pipelined (chunk c+1 global loads in flight during chunk c
// MFMA). W fragments computed once per block from mats (L2-hot) + head_w (s_load).
// x split hi/mid/lo into 3 LDS planes [64][128] bf16 (48 KB), XOR-swizzled
// byte ^= (row&7)<<4 -> ushort8 writes and b128 reads both at the 8/bank floor.
__global__ __launch_bounds__(256, 2) void fused_kernel(const float* __restrict__ x,
                                                       const float* __restrict__ mats,
                                                       const float* __restrict__ head_w,
                                                       const float* __restrict__ head_b_p,
                                                       float* __restrict__ out) {
    __shared__ unsigned short xh[T_DIM * D_DIM / 2 * 2];  // 8192 bf16 = 16 KB
    __shared__ unsigned short xm[8192];
    __shared__ unsigned short xl[8192];

    const int tid = threadIdx.x;
    const int lane = tid & 63;
    const int tg = tid >> 6;    // wave's t-group
    const int r = lane & 15;    // A row / B col within 16
    const int q = lane >> 4;    // k sub-block / C row group
    const int srow = tid >> 2;  // staging row (0..63)
    const int c4 = tid & 3;     // staging col group (32 elems each)

    // ---- chunk-0 x loads: issue FIRST so latency hides under W prologue ----
    int n0 = blockIdx.x * 64;   // chunk index c*GRID + bid, c=0
    float4 p[8];
    {
        const int gn = n0 + srow;
        const float* xrow = x + (size_t)gn * D_DIM + c4 * 32;
#pragma unroll
        for (int j = 0; j < 8; ++j) {
            p[j] = make_float4(0.f, 0.f, 0.f, 0.f);
            if (gn < N_NODES) p[j] = *reinterpret_cast<const float4*>(xrow + j * 4);
        }
    }

    // ---- W fragments (once per block): reduce over mats, 3-level split ----
    float hw[M_MATS];
#pragma unroll
    for (int m = 0; m < M_MATS; ++m) hw[m] = head_w[m];   // uniform -> s_load

    bf16x8 ah[4], am[4], al[4];
#pragma unroll
    for (int k4 = 0; k4 < 4; ++k4) {
        const float* wp = mats + (tg * 16 + r) * D_DIM + k4 * 32 + q * 8;
        float wa[8];
#pragma unroll
        for (int e = 0; e < 8; ++e) wa[e] = 0.f;
#pragma unroll
        for (int m = 0; m < M_MATS; ++m) {
            float4 v0 = *reinterpret_cast<const float4*>(wp + m * (T_DIM * D_DIM));
            float4 v1 = *reinterpret_cast<const float4*>(wp + m * (T_DIM * D_DIM) + 4);
            wa[0] = fmaf(hw[m], v0.x, wa[0]); wa[1] = fmaf(hw[m], v0.y, wa[1]);
            wa[2] = fmaf(hw[m], v0.z, wa[2]); wa[3] = fmaf(hw[m], v0.w, wa[3]);
            wa[4] = fmaf(hw[m], v1.x, wa[4]); wa[5] = fmaf(hw[m], v1.y, wa[5]);
            wa[6] = fmaf(hw[m], v1.z, wa[6]); wa[7] = fmaf(hw[m], v1.w, wa[7]);
        }
#pragma unroll
        for (int e = 0; e < 8; ++e) {
            unsigned short h_, m_, l_;
            split3(wa[e], h_, m_, l_);
            ah[k4][e] = (short)h_; am[k4][e] = (short)m_; al[k4][e] = (short)l_;
        }
    }
    const float hb = head_b_p[0];

    // split 32 elems (8 float4) -> 4 swizzled ushort8 units per plane
#define SPLIT_STORE32(P)                                                        \
    {                                                                           \
        float fv[32];                                                           \
        _Pragma("unroll")                                                       \
        for (int j = 0; j < 8; ++j) {                                           \
            fv[j * 4 + 0] = (P)[j].x; fv[j * 4 + 1] = (P)[j].y;                 \
            fv[j * 4 + 2] = (P)[j].z; fv[j * 4 + 3] = (P)[j].w;                 \
        }                                                                       \
        _Pragma("unroll")                                                       \
        for (int u = 0; u < 4; ++u) {                                           \
            ushort8 H, M, L;                                                    \
            _Pragma("unroll")                                                   \
            for (int e = 0; e < 8; ++e) {                                       \
                unsigned short h_, m_, l_;                                      \
                split3(fv[u * 8 + e], h_, m_, l_);                              \
                H[e] = h_; M[e] = m_; L[e] = l_;                                \
            }                                                                   \
            int unit = srow * 16 + c4 * 4 + u;                                  \
            int byte = (unit << 4) ^ ((srow & 7) << 4);                         \
            *reinterpret_cast<ushort8*>(reinterpret_cast<char*>(xh) + byte) = H;\
            *reinterpret_cast<ushort8*>(reinterpret_cast<char*>(xm) + byte) = M;\
            *reinterpret_cast<ushort8*>(reinterpret_cast<char*>(xl) + byte) = L;\
        }                                                                       \
    }

    SPLIT_STORE32(p);
    __syncthreads();

    // ---- 3 pipelined chunks ----
#pragma unroll
    for (int c = 0; c < CPB; ++c) {
        n0 = (c * GRID + (int)blockIdx.x) * 64;

        // issue next chunk's global loads (in flight during MFMA below)
        float4 pn[8];
        if (c + 1 < CPB) {
            const int gn = ((c + 1) * GRID + (int)blockIdx.x) * 64 + srow;
            const float* xrow = x + (size_t)gn * D_DIM + c4 * 32;
#pragma unroll
            for (int j = 0; j < 8; ++j) {
                pn[j] = make_float4(0.f, 0.f, 0.f, 0.f);
                if (gn < N_NODES) pn[j] = *reinterpret_cast<const float4*>(xrow + j * 4);
            }
        }

        // ---- MFMA: 4 k-tiles, nt in pairs (acc reuse distance 2) ----
        f32x4 acc[4];
#pragma unroll
        for (int nt = 0; nt < 4; ++nt) acc[nt] = (f32x4){0.f, 0.f, 0.f, 0.f};

#pragma unroll
        for (int k4 = 0; k4 < 4; ++k4) {
#pragma unroll
            for (int np = 0; np < 4; np += 2) {
                int e0 = ((np * 16 + r) * D_DIM + k4 * 32 + q * 8);
                int b0 = (e0 << 1) ^ ((r & 7) << 4);
                int e1 = (((np + 1) * 16 + r) * D_DIM + k4 * 32 + q * 8);
                int b1 = (e1 << 1) ^ ((r & 7) << 4);
                bf16x8 bh0 = *reinterpret_cast<const bf16x8*>(reinterpret_cast<const char*>(xh) + b0);
                bf16x8 bm0 = *reinterpret_cast<const bf16x8*>(reinterpret_cast<const char*>(xm) + b0);
                bf16x8 bl0 = *reinterpret_cast<const bf16x8*>(reinterpret_cast<const char*>(xl) + b0);
                bf16x8 bh1 = *reinterpret_cast<const bf16x8*>(reinterpret_cast<const char*>(xh) + b1);
                bf16x8 bm1 = *reinterpret_cast<const bf16x8*>(reinterpret_cast<const char*>(xm) + b1);
                bf16x8 bl1 = *reinterpret_cast<const bf16x8*>(reinterpret_cast<const char*>(xl) + b1);
                acc[np]     = __builtin_amdgcn_mfma_f32_16x16x32_bf16(ah[k4], bh0, acc[np], 0, 0, 0);
                acc[np + 1] = __builtin_amdgcn_mfma_f32_16x16x32_bf16(ah[k4], bh1, acc[np + 1], 0, 0, 0);
                acc[np]     = __builtin_amdgcn_mfma_f32_16x16x32_bf16(ah[k4], bm0, acc[np], 0, 0, 0);
                acc[np + 1] = __builtin_amdgcn_mfma_f32_16x16x32_bf16(ah[k4], bm1, acc[np + 1], 0, 0, 0);
                acc[np]     = __builtin_amdgcn_mfma_f32_16x16x32_bf16(am[k4], bh0, acc[np], 0, 0, 0);
                acc[np + 1] = __builtin_amdgcn_mfma_f32_16x16x32_bf16(am[k4], bh1, acc[np + 1], 0, 0, 0);
                acc[np]     = __builtin_amdgcn_mfma_f32_16x16x32_bf16(ah[k4], bl0, acc[np], 0, 0, 0);
                acc[np + 1] = __builtin_amdgcn_mfma_f32_16x16x32_bf16(ah[k4], bl1, acc[np + 1], 0, 0, 0);
                acc[np]     = __builtin_amdgcn_mfma_f32_16x16x32_bf16(al[k4], bh0, acc[np], 0, 0, 0);
                acc[np + 1] = __builtin_amdgcn_mfma_f32_16x16x32_bf16(al[k4], bh1, acc[np + 1], 0, 0, 0);
                acc[np]     = __builtin_amdgcn_mfma_f32_16x16x32_bf16(am[k4], bm0, acc[np], 0, 0, 0);
                acc[np + 1] = __builtin_amdgcn_mfma_f32_16x16x32_bf16(am[k4], bm1, acc[np + 1], 0, 0, 0);
            }
        }

        // ---- epilogue: sigmoid + prune + store ----
#pragma unroll
        for (int nt = 0; nt < 4; ++nt) {
            int n = n0 + nt * 16 + r;
            if (n < N_NODES) {
#pragma unroll
                for (int i = 0; i < 4; ++i) {
                    int t = tg * 16 + q * 4 + i;
                    float v = acc[nt][i] + hb;
                    float s = 1.0f / (1.0f + __expf(-v));
                    if (s < CROSS_PRUNE) s = 0.0f;
                    out[(size_t)t * N_NODES + n] = s;
                }
            }
        }

        // ---- rotate LDS to next chunk ----
        if (c + 1 < CPB) {
            __syncthreads();        // all waves done reading current LDS
            SPLIT_STORE32(pn);
            __syncthreads();        // next chunk visible
        }
    }
#undef SPLIT_STORE32
}

extern "C" void kernel_launch(void* const* d_in, const int* in_sizes, int n_in,
                              void* d_out, int out_size, void* d_ws, size_t ws_size,
                              hipStream_t stream) {
    const float* x      = (const float*)d_in[0];  // [N, D]
    const float* mats   = (const float*)d_in[1];  // [M, T, D]
    const float* head_w = (const float*)d_in[2];  // [M]
    const float* head_b = (const float*)d_in[3];  // [] (1 element)
    float* out = (float*)d_out;                   // [T, N] f32

    hipLaunchKernelGGL(fused_kernel, dim3(GRID), dim3(256), 0, stream,
                       x, mats, head_w, head_b, out);
}

// Round 10
// 48.234 us; speedup vs baseline: 1.1867x; 1.1867x over previous
//
#include <hip/hip_runtime.h>
#include <hip/hip_bf16.h>

#define N_NODES 100000
#define T_DIM 64
#define D_DIM 128
#define M_MATS 8
#define CROSS_PRUNE 0.1f
#define WPLANE (T_DIM * D_DIM)   // 8192 elems per W split plane

typedef __attribute__((ext_vector_type(8))) short bf16x8;    // MFMA A/B fragment
typedef __attribute__((ext_vector_type(4))) float f32x4;     // MFMA accumulator

// RNE 3-level split via native casts. r1 = v - bf(v), r2 = r1 - bf(r1) exact (Sterbenz).
__device__ __forceinline__ void split3(float v, unsigned short& h,
                                       unsigned short& m, unsigned short& l) {
    __hip_bfloat16 bh = __float2bfloat16(v);
    float fh = __bfloat162float(bh);
    float r1 = v - fh;
    __hip_bfloat16 bm = __float2bfloat16(r1);
    float fm = __bfloat162float(bm);
    float r2 = r1 - fm;
    __hip_bfloat16 bl = __float2bfloat16(r2);
    h = __builtin_bit_cast(unsigned short, bh);
    m = __builtin_bit_cast(unsigned short, bm);
    l = __builtin_bit_cast(unsigned short, bl);
}

// split 8 consecutive f32 (two float4) into three bf16x8 fragments
__device__ __forceinline__ void split8(float4 v0, float4 v1,
                                       bf16x8& H, bf16x8& M, bf16x8& L) {
    float fv[8] = {v0.x, v0.y, v0.z, v0.w, v1.x, v1.y, v1.z, v1.w};
#pragma unroll
    for (int e = 0; e < 8; ++e) {
        unsigned short h_, m_, l_;
        split3(fv[e], h_, m_, l_);
        H[e] = (short)h_; M[e] = (short)m_; L[e] = (short)l_;
    }
}

// ---- Kernel 1: w[t][d] = sum_m head_w[m]*mats[m][t][d], 3-level split -> wh/wm/wl ----
__global__ __launch_bounds__(256) void wsplit_kernel(const float* __restrict__ mats,
                                                     const float* __restrict__ head_w,
                                                     unsigned short* __restrict__ wh,
                                                     unsigned short* __restrict__ wm,
                                                     unsigned short* __restrict__ wl) {
    int i = blockIdx.x * 256 + threadIdx.x;
    if (i < WPLANE) {
        float acc = 0.f;
#pragma unroll
        for (int m = 0; m < M_MATS; ++m)
            acc += head_w[m] * mats[m * WPLANE + i];
        unsigned short h, mm, l;
        split3(acc, h, mm, l);
        wh[i] = h; wm[i] = mm; wl[i] = l;
    }
}

// ---- Kernel 2: NO LDS, NO barriers. 1563 blocks x 4 independent waves. ----
// Wave tg owns t in [tg*16, tg*16+16) for the block's 64 n. B-fragments loaded
// straight from global x (L2/L3-resident: 32 KB/block working set, lesson: don't
// stage cache-fit data). x split 3-level in-register (VALU is idle). W fragments:
// 12 hoisted b128 loads from kernel-1 planes (L2-hot). 6-product bf16-split MFMA.
__global__ __launch_bounds__(256, 4) void cross_kernel(const float* __restrict__ x,
                                                       const unsigned short* __restrict__ wh,
                                                       const unsigned short* __restrict__ wm,
                                                       const unsigned short* __restrict__ wl,
                                                       const float* __restrict__ head_b_p,
                                                       float* __restrict__ out) {
    const int tid = threadIdx.x;
    const int lane = tid & 63;
    const int tg = tid >> 6;    // wave's t-group
    const int r = lane & 15;    // A row / B col (n offset) within 16
    const int q = lane >> 4;    // k sub-block / C row group
    const int n0 = blockIdx.x * 64;

    // ---- A fragments: 12 b128 loads, hoisted (independent, issue together) ----
    bf16x8 ah[4], am[4], al[4];
#pragma unroll
    for (int k4 = 0; k4 < 4; ++k4) {
        int eo = (tg * 16 + r) * D_DIM + k4 * 32 + q * 8;
        ah[k4] = *reinterpret_cast<const bf16x8*>(wh + eo);
        am[k4] = *reinterpret_cast<const bf16x8*>(wm + eo);
        al[k4] = *reinterpret_cast<const bf16x8*>(wl + eo);
    }

    f32x4 acc[4];
#pragma unroll
    for (int nt = 0; nt < 4; ++nt) acc[nt] = (f32x4){0.f, 0.f, 0.f, 0.f};

    const float4 z4 = make_float4(0.f, 0.f, 0.f, 0.f);

#pragma unroll
    for (int k4 = 0; k4 < 4; ++k4) {
        const int dofs = k4 * 32 + q * 8;   // this lane's k-slice within x row
#pragma unroll
        for (int np = 0; np < 4; np += 2) {
            // two B rows (n values) for this lane
            const int na = n0 + np * 16 + r;
            const int nb = na + 16;
            float4 a0 = z4, a1 = z4, b0 = z4, b1 = z4;
            if (na < N_NODES) {
                const float* pa = x + (size_t)na * D_DIM + dofs;
                a0 = *reinterpret_cast<const float4*>(pa);
                a1 = *reinterpret_cast<const float4*>(pa + 4);
            }
            if (nb < N_NODES) {
                const float* pb = x + (size_t)nb * D_DIM + dofs;
                b0 = *reinterpret_cast<const float4*>(pb);
                b1 = *reinterpret_cast<const float4*>(pb + 4);
            }
            bf16x8 bhA, bmA, blA, bhB, bmB, blB;
            split8(a0, a1, bhA, bmA, blA);
            split8(b0, b1, bhB, bmB, blB);

            // 6 products, np/np+1 interleaved (acc reuse distance 2) — R8 order
            acc[np]     = __builtin_amdgcn_mfma_f32_16x16x32_bf16(ah[k4], bhA, acc[np], 0, 0, 0);
            acc[np + 1] = __builtin_amdgcn_mfma_f32_16x16x32_bf16(ah[k4], bhB, acc[np + 1], 0, 0, 0);
            acc[np]     = __builtin_amdgcn_mfma_f32_16x16x32_bf16(ah[k4], bmA, acc[np], 0, 0, 0);
            acc[np + 1] = __builtin_amdgcn_mfma_f32_16x16x32_bf16(ah[k4], bmB, acc[np + 1], 0, 0, 0);
            acc[np]     = __builtin_amdgcn_mfma_f32_16x16x32_bf16(am[k4], bhA, acc[np], 0, 0, 0);
            acc[np + 1] = __builtin_amdgcn_mfma_f32_16x16x32_bf16(am[k4], bhB, acc[np + 1], 0, 0, 0);
            acc[np]     = __builtin_amdgcn_mfma_f32_16x16x32_bf16(ah[k4], blA, acc[np], 0, 0, 0);
            acc[np + 1] = __builtin_amdgcn_mfma_f32_16x16x32_bf16(ah[k4], blB, acc[np + 1], 0, 0, 0);
            acc[np]     = __builtin_amdgcn_mfma_f32_16x16x32_bf16(al[k4], bhA, acc[np], 0, 0, 0);
            acc[np + 1] = __builtin_amdgcn_mfma_f32_16x16x32_bf16(al[k4], bhB, acc[np + 1], 0, 0, 0);
            acc[np]     = __builtin_amdgcn_mfma_f32_16x16x32_bf16(am[k4], bmA, acc[np], 0, 0, 0);
            acc[np + 1] = __builtin_amdgcn_mfma_f32_16x16x32_bf16(am[k4], bmB, acc[np + 1], 0, 0, 0);
        }
    }

    // ---- epilogue: sigmoid + prune + store (C: col=r -> n, row=q*4+i -> t) ----
    const float hb = head_b_p[0];
#pragma unroll
    for (int nt = 0; nt < 4; ++nt) {
        int n = n0 + nt * 16 + r;
        if (n < N_NODES) {
#pragma unroll
            for (int i = 0; i < 4; ++i) {
                int t = tg * 16 + q * 4 + i;
                float v = acc[nt][i] + hb;
                float s = 1.0f / (1.0f + __expf(-v));
                if (s < CROSS_PRUNE) s = 0.0f;
                out[(size_t)t * N_NODES + n] = s;
            }
        }
    }
}

extern "C" void kernel_launch(void* const* d_in, const int* in_sizes, int n_in,
                              void* d_out, int out_size, void* d_ws, size_t ws_size,
                              hipStream_t stream) {
    const float* x      = (const float*)d_in[0];  // [N, D]
    const float* mats   = (const float*)d_in[1];  // [M, T, D]
    const float* head_w = (const float*)d_in[2];  // [M]
    const float* head_b = (const float*)d_in[3];  // [] (1 element)
    float* out = (float*)d_out;                   // [T, N] f32

    unsigned short* wh = (unsigned short*)d_ws;   // 3 bf16 planes, 16 KB each
    unsigned short* wm = wh + WPLANE;
    unsigned short* wl = wm + WPLANE;

    hipLaunchKernelGGL(wsplit_kernel, dim3((WPLANE + 255) / 256), dim3(256), 0, stream,
                       mats, head_w, wh, wm, wl);

    int nblk = (N_NODES + 63) / 64;   // 1563
    hipLaunchKernelGGL(cross_kernel, dim3(nblk), dim3(256), 0, stream,
                       x, wh, wm, wl, head_b, out);
}

// Round 11
// 40.833 us; speedup vs baseline: 1.4018x; 1.1813x over previous
//
#include <hip/hip_runtime.h>
#include <hip/hip_bf16.h>

#define N_NODES 100000
#define T_DIM 64
#define D_DIM 128
#define M_MATS 8
#define CROSS_PRUNE 0.1f
#define WPLANE (T_DIM * D_DIM)   // 8192 elems per W split plane

typedef __attribute__((ext_vector_type(8))) short bf16x8;     // MFMA A/B fragment
typedef __attribute__((ext_vector_type(16))) float f32x16;    // 32x32 accumulator
typedef __attribute__((ext_vector_type(8))) unsigned short ushort8;

// RNE 3-level split via native casts. r1 = v - bf(v), r2 = r1 - bf(r1) exact (Sterbenz).
__device__ __forceinline__ void split3(float v, unsigned short& h,
                                       unsigned short& m, unsigned short& l) {
    __hip_bfloat16 bh = __float2bfloat16(v);
    float fh = __bfloat162float(bh);
    float r1 = v - fh;
    __hip_bfloat16 bm = __float2bfloat16(r1);
    float fm = __bfloat162float(bm);
    float r2 = r1 - fm;
    __hip_bfloat16 bl = __float2bfloat16(r2);
    h = __builtin_bit_cast(unsigned short, bh);
    m = __builtin_bit_cast(unsigned short, bm);
    l = __builtin_bit_cast(unsigned short, bl);
}

// ---- Kernel 1: w[t][d] = sum_m head_w[m]*mats[m][t][d], 3-level split -> wh/wm/wl ----
__global__ __launch_bounds__(256) void wsplit_kernel(const float* __restrict__ mats,
                                                     const float* __restrict__ head_w,
                                                     unsigned short* __restrict__ wh,
                                                     unsigned short* __restrict__ wm,
                                                     unsigned short* __restrict__ wl) {
    int i = blockIdx.x * 256 + threadIdx.x;
    if (i < WPLANE) {
        float acc = 0.f;
#pragma unroll
        for (int m = 0; m < M_MATS; ++m)
            acc += head_w[m] * mats[m * WPLANE + i];
        unsigned short h, mm, l;
        split3(acc, h, mm, l);
        wh[i] = h; wm[i] = mm; wl[i] = l;
    }
}

// ---- Kernel 2: 32x32x16 MFMA, 3-level bf16-split, sigmoid + prune ----
// Block: 256 thr = 4 waves = (th,nh) in 2x2; wave owns 32t x 32n of the block's
// 64n chunk. x split into 3 LDS planes [64][64] bf16 per 64-d half (24 KB),
// XOR-swizzled byte ^= (row&7)<<4 (writes AND 32-row b128 reads at 8/bank floor).
// A streamed from pre-split W planes (L2-hot). 6 products: hh,hm,mh,hl,lh,mm.
__global__ __launch_bounds__(256, 5) void cross_kernel(const float* __restrict__ x,
                                                       const unsigned short* __restrict__ wh,
                                                       const unsigned short* __restrict__ wm,
                                                       const unsigned short* __restrict__ wl,
                                                       const float* __restrict__ head_b_p,
                                                       float* __restrict__ out) {
    __shared__ unsigned short xh[64 * 64];
    __shared__ unsigned short xm[64 * 64];
    __shared__ unsigned short xl[64 * 64];

    const int tid = threadIdx.x;
    const int n0 = blockIdx.x * 64;
    const int lane = tid & 63;
    const int w = tid >> 6;
    const int th = w >> 1;      // t-half (0/1)
    const int nh = w & 1;       // n-half (0/1)
    const int cl = lane & 31;   // A row (t) / B col (n) offset
    const int kh = lane >> 5;   // k-half within 16-k step

    const float hb = head_b_p[0];

    // ---- x global loads: row = tid>>2, cols (tid&3)*16 .. +16, both halves ----
    const int srow = tid >> 2;
    const int scol = (tid & 3) * 16;
    const int gn_s = n0 + srow;
    const float* xrow = x + (size_t)gn_s * D_DIM + scol;

    float4 p0[4], p1[4];
#pragma unroll
    for (int j = 0; j < 4; ++j) {
        p0[j] = make_float4(0.f, 0.f, 0.f, 0.f);
        p1[j] = p0[j];
        if (gn_s < N_NODES) {
            p0[j] = *reinterpret_cast<const float4*>(xrow + j * 4);        // half 0
            p1[j] = *reinterpret_cast<const float4*>(xrow + 64 + j * 4);   // half 1
        }
    }

    // split 16 elems and store as 2 swizzled ushort8 per plane (R8-verified pattern)
#define SPLIT_STORE16(P)                                                        \
    {                                                                           \
        float fv[16];                                                           \
        _Pragma("unroll")                                                       \
        for (int j = 0; j < 4; ++j) {                                           \
            fv[j * 4 + 0] = (P)[j].x; fv[j * 4 + 1] = (P)[j].y;                 \
            fv[j * 4 + 2] = (P)[j].z; fv[j * 4 + 3] = (P)[j].w;                 \
        }                                                                       \
        _Pragma("unroll")                                                       \
        for (int u = 0; u < 2; ++u) {                                           \
            ushort8 H, M, L;                                                    \
            _Pragma("unroll")                                                   \
            for (int e = 0; e < 8; ++e) {                                       \
                unsigned short h_, m_, l_;                                      \
                split3(fv[u * 8 + e], h_, m_, l_);                              \
                H[e] = h_; M[e] = m_; L[e] = l_;                                \
            }                                                                   \
            int unit = srow * 8 + (tid & 3) * 2 + u;                            \
            int byte = (unit << 4) ^ ((srow & 7) << 4);                         \
            *reinterpret_cast<ushort8*>(reinterpret_cast<char*>(xh) + byte) = H;\
            *reinterpret_cast<ushort8*>(reinterpret_cast<char*>(xm) + byte) = M;\
            *reinterpret_cast<ushort8*>(reinterpret_cast<char*>(xl) + byte) = L;\
        }                                                                       \
    }

    SPLIT_STORE16(p0);
    __syncthreads();

    f32x16 acc;
#pragma unroll
    for (int i = 0; i < 16; ++i) acc[i] = 0.f;

#pragma unroll
    for (int half = 0; half < 2; ++half) {
        if (half == 1) {
            __syncthreads();   // half-0 readers done
            SPLIT_STORE16(p1);
            __syncthreads();
        }

#pragma unroll
        for (int kstep = 0; kstep < 4; ++kstep) {
            // A fragments: W[th*32+cl][half*64 + kstep*16 + kh*8 .. +8), 3 planes (global, L2-hot)
            const int eoA = (th * 32 + cl) * D_DIM + half * 64 + kstep * 16 + kh * 8;
            bf16x8 Ah = *reinterpret_cast<const bf16x8*>(wh + eoA);
            bf16x8 Am = *reinterpret_cast<const bf16x8*>(wm + eoA);
            bf16x8 Al = *reinterpret_cast<const bf16x8*>(wl + eoA);

            // B fragments: x rows nh*32+cl, local k = kstep*16 + kh*8 (swizzled LDS b128)
            const int row = nh * 32 + cl;
            const int unit = row * 8 + kstep * 2 + kh;
            const int byte = (unit << 4) ^ ((row & 7) << 4);
            bf16x8 Bh = *reinterpret_cast<const bf16x8*>(reinterpret_cast<const char*>(xh) + byte);
            bf16x8 Bm = *reinterpret_cast<const bf16x8*>(reinterpret_cast<const char*>(xm) + byte);
            bf16x8 Bl = *reinterpret_cast<const bf16x8*>(reinterpret_cast<const char*>(xl) + byte);

            acc = __builtin_amdgcn_mfma_f32_32x32x16_bf16(Ah, Bh, acc, 0, 0, 0);
            acc = __builtin_amdgcn_mfma_f32_32x32x16_bf16(Ah, Bm, acc, 0, 0, 0);
            acc = __builtin_amdgcn_mfma_f32_32x32x16_bf16(Am, Bh, acc, 0, 0, 0);
            acc = __builtin_amdgcn_mfma_f32_32x32x16_bf16(Ah, Bl, acc, 0, 0, 0);
            acc = __builtin_amdgcn_mfma_f32_32x32x16_bf16(Al, Bh, acc, 0, 0, 0);
            acc = __builtin_amdgcn_mfma_f32_32x32x16_bf16(Am, Bm, acc, 0, 0, 0);
        }
    }

    // ---- epilogue: C/D 32x32 map: col(n)=lane&31, row(t)=(reg&3)+8*(reg>>2)+4*kh ----
    const int n = n0 + nh * 32 + cl;
    if (n < N_NODES) {
#pragma unroll
        for (int reg = 0; reg < 16; ++reg) {
            int t = th * 32 + (reg & 3) + 8 * (reg >> 2) + 4 * kh;
            float v = acc[reg] + hb;
            float s = 1.0f / (1.0f + __expf(-v));
            if (s < CROSS_PRUNE) s = 0.0f;
            out[(size_t)t * N_NODES + n] = s;
        }
    }
#undef SPLIT_STORE16
}

extern "C" void kernel_launch(void* const* d_in, const int* in_sizes, int n_in,
                              void* d_out, int out_size, void* d_ws, size_t ws_size,
                              hipStream_t stream) {
    const float* x      = (const float*)d_in[0];  // [N, D]
    const float* mats   = (const float*)d_in[1];  // [M, T, D]
    const float* head_w = (const float*)d_in[2];  // [M]
    const float* head_b = (const float*)d_in[3];  // [] (1 element)
    float* out = (float*)d_out;                   // [T, N] f32

    unsigned short* wh = (unsigned short*)d_ws;   // 3 bf16 planes, 16 KB each
    unsigned short* wm = wh + WPLANE;
    unsigned short* wl = wm + WPLANE;

    hipLaunchKernelGGL(wsplit_kernel, dim3((WPLANE + 255) / 256), dim3(256), 0, stream,
                       mats, head_w, wh, wm, wl);

    int nblk = (N_NODES + 63) / 64;   // 1563
    hipLaunchKernelGGL(cross_kernel, dim3(nblk), dim3(256), 0, stream,
                       x, wh, wm, wl, head_b, out);
}

// Round 12
// 36.370 us; speedup vs baseline: 1.5739x; 1.1227x over previous
//
#include <hip/hip_runtime.h>
#include <hip/hip_bf16.h>

#define N_NODES 100000
#define T_DIM 64
#define D_DIM 128
#define M_MATS 8
#define CROSS_PRUNE 0.1f
#define WPLANE (T_DIM * D_DIM)   // 8192 elems per W split plane
#define GRID 782                 // blocks; CPB chunks each covers 1564 >= 1563 chunks
#define CPB 2

typedef __attribute__((ext_vector_type(8))) short bf16x8;    // MFMA A/B fragment
typedef __attribute__((ext_vector_type(4))) float f32x4;     // MFMA accumulator
typedef __attribute__((ext_vector_type(8))) unsigned short ushort8;

// RNE 3-level split via native casts. r1 = v - bf(v), r2 = r1 - bf(r1) exact (Sterbenz).
__device__ __forceinline__ void split3(float v, unsigned short& h,
                                       unsigned short& m, unsigned short& l) {
    __hip_bfloat16 bh = __float2bfloat16(v);
    float fh = __bfloat162float(bh);
    float r1 = v - fh;
    __hip_bfloat16 bm = __float2bfloat16(r1);
    float fm = __bfloat162float(bm);
    float r2 = r1 - fm;
    __hip_bfloat16 bl = __float2bfloat16(r2);
    h = __builtin_bit_cast(unsigned short, bh);
    m = __builtin_bit_cast(unsigned short, bm);
    l = __builtin_bit_cast(unsigned short, bl);
}

// ---- Kernel 1: w[t][d] = sum_m head_w[m]*mats[m][t][d], 3-level split -> wh/wm/wl ----
__global__ __launch_bounds__(256) void wsplit_kernel(const float* __restrict__ mats,
                                                     const float* __restrict__ head_w,
                                                     unsigned short* __restrict__ wh,
                                                     unsigned short* __restrict__ wm,
                                                     unsigned short* __restrict__ wl) {
    int i = blockIdx.x * 256 + threadIdx.x;
    if (i < WPLANE) {
        float acc = 0.f;
#pragma unroll
        for (int m = 0; m < M_MATS; ++m)
            acc += head_w[m] * mats[m * WPLANE + i];
        unsigned short h, mm, l;
        split3(acc, h, mm, l);
        wh[i] = h; wm[i] = mm; wl[i] = l;
    }
}

// ---- Kernel 2: R8 structure + CPB=2 chunk loop with cross-chunk prefetch ----
// Block: 256 thr (4 waves); per chunk owns 64 n; wave tg owns t in [tg*16,+16).
// x split hi/mid/lo into 3 LDS planes [64][64] bf16 per 64-d half (24 KB),
// XOR-swizzled byte ^= (row&7)<<4 (writes AND b128 reads at 8/bank floor).
// Next chunk's global x loads issue into freed p-regs BEFORE half-1 compute.
__global__ __launch_bounds__(256, 4) void cross_kernel(const float* __restrict__ x,
                                                       const unsigned short* __restrict__ wh,
                                                       const unsigned short* __restrict__ wm,
                                                       const unsigned short* __restrict__ wl,
                                                       const float* __restrict__ head_b_p,
                                                       float* __restrict__ out) {
    __shared__ unsigned short xh[64 * 64];
    __shared__ unsigned short xm[64 * 64];
    __shared__ unsigned short xl[64 * 64];

    const int tid = threadIdx.x;
    const int lane = tid & 63;
    const int tg = tid >> 6;    // wave's t-group
    const int r = lane & 15;    // A row / B col within 16
    const int q = lane >> 4;    // k sub-block / C row group
    const int srow = tid >> 2;  // staging row
    const int scol = (tid & 3) * 16;
    const float hb = head_b_p[0];

    // ---- chunk-0 x loads ----
    float4 p0[4], p1[4];
    {
        const int gn = blockIdx.x * 64 + srow;
        const float* xrow = x + (size_t)gn * D_DIM + scol;
#pragma unroll
        for (int j = 0; j < 4; ++j) {
            p0[j] = make_float4(0.f, 0.f, 0.f, 0.f);
            p1[j] = p0[j];
            if (gn < N_NODES) {
                p0[j] = *reinterpret_cast<const float4*>(xrow + j * 4);
                p1[j] = *reinterpret_cast<const float4*>(xrow + 64 + j * 4);
            }
        }
    }

#define SPLIT_STORE16(P)                                                        \
    {                                                                           \
        float fv[16];                                                           \
        _Pragma("unroll")                                                       \
        for (int j = 0; j < 4; ++j) {                                           \
            fv[j * 4 + 0] = (P)[j].x; fv[j * 4 + 1] = (P)[j].y;                 \
            fv[j * 4 + 2] = (P)[j].z; fv[j * 4 + 3] = (P)[j].w;                 \
        }                                                                       \
        _Pragma("unroll")                                                       \
        for (int u = 0; u < 2; ++u) {                                           \
            ushort8 H, M, L;                                                    \
            _Pragma("unroll")                                                   \
            for (int e = 0; e < 8; ++e) {                                       \
                unsigned short h_, m_, l_;                                      \
                split3(fv[u * 8 + e], h_, m_, l_);                              \
                H[e] = h_; M[e] = m_; L[e] = l_;                                \
            }                                                                   \
            int unit = srow * 8 + (tid & 3) * 2 + u;                            \
            int byte = (unit << 4) ^ ((srow & 7) << 4);                         \
            *reinterpret_cast<ushort8*>(reinterpret_cast<char*>(xh) + byte) = H;\
            *reinterpret_cast<ushort8*>(reinterpret_cast<char*>(xm) + byte) = M;\
            *reinterpret_cast<ushort8*>(reinterpret_cast<char*>(xl) + byte) = L;\
        }                                                                       \
    }

#pragma unroll
    for (int c = 0; c < CPB; ++c) {
        const int n0 = (c * GRID + (int)blockIdx.x) * 64;

        // ---- half 0 stage ----
        SPLIT_STORE16(p0);
        __syncthreads();

        f32x4 acc[4];
#pragma unroll
        for (int nt = 0; nt < 4; ++nt) acc[nt] = (f32x4){0.f, 0.f, 0.f, 0.f};

        // ---- half 0 compute ----
        {
            bf16x8 ah[2], am[2], al[2];
#pragma unroll
            for (int k4 = 0; k4 < 2; ++k4) {
                int eo = (tg * 16 + r) * D_DIM + k4 * 32 + q * 8;
                ah[k4] = *reinterpret_cast<const bf16x8*>(wh + eo);
                am[k4] = *reinterpret_cast<const bf16x8*>(wm + eo);
                al[k4] = *reinterpret_cast<const bf16x8*>(wl + eo);
            }
#pragma unroll
            for (int k4 = 0; k4 < 2; ++k4) {
#pragma unroll
                for (int np = 0; np < 4; np += 2) {
                    int e0 = ((np * 16 + r) * 64 + k4 * 32 + q * 8);
                    int b0 = (e0 << 1) ^ ((r & 7) << 4);
                    int e1 = (((np + 1) * 16 + r) * 64 + k4 * 32 + q * 8);
                    int b1 = (e1 << 1) ^ ((r & 7) << 4);
                    bf16x8 bh0 = *reinterpret_cast<const bf16x8*>(reinterpret_cast<const char*>(xh) + b0);
                    bf16x8 bm0 = *reinterpret_cast<const bf16x8*>(reinterpret_cast<const char*>(xm) + b0);
                    bf16x8 bl0 = *reinterpret_cast<const bf16x8*>(reinterpret_cast<const char*>(xl) + b0);
                    bf16x8 bh1 = *reinterpret_cast<const bf16x8*>(reinterpret_cast<const char*>(xh) + b1);
                    bf16x8 bm1 = *reinterpret_cast<const bf16x8*>(reinterpret_cast<const char*>(xm) + b1);
                    bf16x8 bl1 = *reinterpret_cast<const bf16x8*>(reinterpret_cast<const char*>(xl) + b1);
                    acc[np]     = __builtin_amdgcn_mfma_f32_16x16x32_bf16(ah[k4], bh0, acc[np], 0, 0, 0);
                    acc[np + 1] = __builtin_amdgcn_mfma_f32_16x16x32_bf16(ah[k4], bh1, acc[np + 1], 0, 0, 0);
                    acc[np]     = __builtin_amdgcn_mfma_f32_16x16x32_bf16(ah[k4], bm0, acc[np], 0, 0, 0);
                    acc[np + 1] = __builtin_amdgcn_mfma_f32_16x16x32_bf16(ah[k4], bm1, acc[np + 1], 0, 0, 0);
                    acc[np]     = __builtin_amdgcn_mfma_f32_16x16x32_bf16(am[k4], bh0, acc[np], 0, 0, 0);
                    acc[np + 1] = __builtin_amdgcn_mfma_f32_16x16x32_bf16(am[k4], bh1, acc[np + 1], 0, 0, 0);
                    acc[np]     = __builtin_amdgcn_mfma_f32_16x16x32_bf16(ah[k4], bl0, acc[np], 0, 0, 0);
                    acc[np + 1] = __builtin_amdgcn_mfma_f32_16x16x32_bf16(ah[k4], bl1, acc[np + 1], 0, 0, 0);
                    acc[np]     = __builtin_amdgcn_mfma_f32_16x16x32_bf16(al[k4], bh0, acc[np], 0, 0, 0);
                    acc[np + 1] = __builtin_amdgcn_mfma_f32_16x16x32_bf16(al[k4], bh1, acc[np + 1], 0, 0, 0);
                    acc[np]     = __builtin_amdgcn_mfma_f32_16x16x32_bf16(am[k4], bm0, acc[np], 0, 0, 0);
                    acc[np + 1] = __builtin_amdgcn_mfma_f32_16x16x32_bf16(am[k4], bm1, acc[np + 1], 0, 0, 0);
                }
            }
        }

        // ---- half 1 stage ----
        __syncthreads();
        SPLIT_STORE16(p1);
        __syncthreads();

        // ---- prefetch next chunk into freed p-regs (hides under half-1 + epilogue) ----
        if (c + 1 < CPB) {
            const int gn = ((c + 1) * GRID + (int)blockIdx.x) * 64 + srow;
            const float* xrow = x + (size_t)gn * D_DIM + scol;
#pragma unroll
            for (int j = 0; j < 4; ++j) {
                float4 a = make_float4(0.f, 0.f, 0.f, 0.f);
                float4 b = a;
                if (gn < N_NODES) {
                    a = *reinterpret_cast<const float4*>(xrow + j * 4);
                    b = *reinterpret_cast<const float4*>(xrow + 64 + j * 4);
                }
                p0[j] = a; p1[j] = b;
            }
        }

        // ---- half 1 compute ----
        {
            bf16x8 ah[2], am[2], al[2];
#pragma unroll
            for (int k4 = 0; k4 < 2; ++k4) {
                int eo = (tg * 16 + r) * D_DIM + 64 + k4 * 32 + q * 8;
                ah[k4] = *reinterpret_cast<const bf16x8*>(wh + eo);
                am[k4] = *reinterpret_cast<const bf16x8*>(wm + eo);
                al[k4] = *reinterpret_cast<const bf16x8*>(wl + eo);
            }
#pragma unroll
            for (int k4 = 0; k4 < 2; ++k4) {
#pragma unroll
                for (int np = 0; np < 4; np += 2) {
                    int e0 = ((np * 16 + r) * 64 + k4 * 32 + q * 8);
                    int b0 = (e0 << 1) ^ ((r & 7) << 4);
                    int e1 = (((np + 1) * 16 + r) * 64 + k4 * 32 + q * 8);
                    int b1 = (e1 << 1) ^ ((r & 7) << 4);
                    bf16x8 bh0 = *reinterpret_cast<const bf16x8*>(reinterpret_cast<const char*>(xh) + b0);
                    bf16x8 bm0 = *reinterpret_cast<const bf16x8*>(reinterpret_cast<const char*>(xm) + b0);
                    bf16x8 bl0 = *reinterpret_cast<const bf16x8*>(reinterpret_cast<const char*>(xl) + b0);
                    bf16x8 bh1 = *reinterpret_cast<const bf16x8*>(reinterpret_cast<const char*>(xh) + b1);
                    bf16x8 bm1 = *reinterpret_cast<const bf16x8*>(reinterpret_cast<const char*>(xm) + b1);
                    bf16x8 bl1 = *reinterpret_cast<const bf16x8*>(reinterpret_cast<const char*>(xl) + b1);
                    acc[np]     = __builtin_amdgcn_mfma_f32_16x16x32_bf16(ah[k4], bh0, acc[np], 0, 0, 0);
                    acc[np + 1] = __builtin_amdgcn_mfma_f32_16x16x32_bf16(ah[k4], bh1, acc[np + 1], 0, 0, 0);
                    acc[np]     = __builtin_amdgcn_mfma_f32_16x16x32_bf16(ah[k4], bm0, acc[np], 0, 0, 0);
                    acc[np + 1] = __builtin_amdgcn_mfma_f32_16x16x32_bf16(ah[k4], bm1, acc[np + 1], 0, 0, 0);
                    acc[np]     = __builtin_amdgcn_mfma_f32_16x16x32_bf16(am[k4], bh0, acc[np], 0, 0, 0);
                    acc[np + 1] = __builtin_amdgcn_mfma_f32_16x16x32_bf16(am[k4], bh1, acc[np + 1], 0, 0, 0);
                    acc[np]     = __builtin_amdgcn_mfma_f32_16x16x32_bf16(ah[k4], bl0, acc[np], 0, 0, 0);
                    acc[np + 1] = __builtin_amdgcn_mfma_f32_16x16x32_bf16(ah[k4], bl1, acc[np + 1], 0, 0, 0);
                    acc[np]     = __builtin_amdgcn_mfma_f32_16x16x32_bf16(al[k4], bh0, acc[np], 0, 0, 0);
                    acc[np + 1] = __builtin_amdgcn_mfma_f32_16x16x32_bf16(al[k4], bh1, acc[np + 1], 0, 0, 0);
                    acc[np]     = __builtin_amdgcn_mfma_f32_16x16x32_bf16(am[k4], bm0, acc[np], 0, 0, 0);
                    acc[np + 1] = __builtin_amdgcn_mfma_f32_16x16x32_bf16(am[k4], bm1, acc[np + 1], 0, 0, 0);
                }
            }
        }

        // ---- epilogue ----
#pragma unroll
        for (int nt = 0; nt < 4; ++nt) {
            int n = n0 + nt * 16 + r;
            if (n < N_NODES) {
#pragma unroll
                for (int i = 0; i < 4; ++i) {
                    int t = tg * 16 + q * 4 + i;
                    float v = acc[nt][i] + hb;
                    float s = 1.0f / (1.0f + __expf(-v));
                    if (s < CROSS_PRUNE) s = 0.0f;
                    out[(size_t)t * N_NODES + n] = s;
                }
            }
        }

        if (c + 1 < CPB) __syncthreads();   // this chunk's h1 reads done before next stage
    }
#undef SPLIT_STORE16
}

extern "C" void kernel_launch(void* const* d_in, const int* in_sizes, int n_in,
                              void* d_out, int out_size, void* d_ws, size_t ws_size,
                              hipStream_t stream) {
    const float* x      = (const float*)d_in[0];  // [N, D]
    const float* mats   = (const float*)d_in[1];  // [M, T, D]
    const float* head_w = (const float*)d_in[2];  // [M]
    const float* head_b = (const float*)d_in[3];  // [] (1 element)
    float* out = (float*)d_out;                   // [T, N] f32

    unsigned short* wh = (unsigned short*)d_ws;   // 3 bf16 planes, 16 KB each
    unsigned short* wm = wh + WPLANE;
    unsigned short* wl = wm + WPLANE;

    hipLaunchKernelGGL(wsplit_kernel, dim3((WPLANE + 255) / 256), dim3(256), 0, stream,
                       mats, head_w, wh, wm, wl);

    hipLaunchKernelGGL(cross_kernel, dim3(GRID), dim3(256), 0, stream,
                       x, wh, wm, wl, head_b, out);
}

// Round 13
// 36.363 us; speedup vs baseline: 1.5741x; 1.0002x over previous
//
#include <hip/hip_runtime.h>
#include <hip/hip_bf16.h>

#define N_NODES 100000
#define T_DIM 64
#define D_DIM 128
#define M_MATS 8
#define CROSS_PRUNE 0.1f
#define WPLANE (T_DIM * D_DIM)   // 8192 elems per W split plane
#define NCHUNK 1563              // ceil(100000/64)
#define GRIDB 512                // 2 blocks/CU exactly (64 KB LDS each)

typedef __attribute__((ext_vector_type(8))) short bf16x8;    // MFMA A/B fragment
typedef __attribute__((ext_vector_type(4))) float f32x4;     // MFMA accumulator

// RNE 3-level split via native casts. r1 = v - bf(v), r2 = r1 - bf(r1) exact (Sterbenz).
__device__ __forceinline__ void split3(float v, unsigned short& h,
                                       unsigned short& m, unsigned short& l) {
    __hip_bfloat16 bh = __float2bfloat16(v);
    float fh = __bfloat162float(bh);
    float r1 = v - fh;
    __hip_bfloat16 bm = __float2bfloat16(r1);
    float fm = __bfloat162float(bm);
    float r2 = r1 - fm;
    __hip_bfloat16 bl = __float2bfloat16(r2);
    h = __builtin_bit_cast(unsigned short, bh);
    m = __builtin_bit_cast(unsigned short, bm);
    l = __builtin_bit_cast(unsigned short, bl);
}

// split 8 f32 (two float4) into three bf16x8 fragments
__device__ __forceinline__ void split8(float4 v0, float4 v1,
                                       bf16x8& H, bf16x8& M, bf16x8& L) {
    float fv[8] = {v0.x, v0.y, v0.z, v0.w, v1.x, v1.y, v1.z, v1.w};
#pragma unroll
    for (int e = 0; e < 8; ++e) {
        unsigned short h_, m_, l_;
        split3(fv[e], h_, m_, l_);
        H[e] = (short)h_; M[e] = (short)m_; L[e] = (short)l_;
    }
}

// ---- Kernel 1: w[t][d] = sum_m head_w[m]*mats[m][t][d], 3-level split -> wh/wm/wl ----
__global__ __launch_bounds__(256) void wsplit_kernel(const float* __restrict__ mats,
                                                     const float* __restrict__ head_w,
                                                     unsigned short* __restrict__ wh,
                                                     unsigned short* __restrict__ wm,
                                                     unsigned short* __restrict__ wl) {
    int i = blockIdx.x * 256 + threadIdx.x;
    if (i < WPLANE) {
        float acc = 0.f;
#pragma unroll
        for (int m = 0; m < M_MATS; ++m)
            acc += head_w[m] * mats[m * WPLANE + i];
        unsigned short h, mm, l;
        split3(acc, h, mm, l);
        wh[i] = h; wm[i] = mm; wl[i] = l;
    }
}

// ---- Kernel 2: T3/T4 pipelined cross kernel ----
// Grid 512 x 256 thr (4 waves), grid-stride over 1563 chunks of 64 n.
// x staged RAW f32 via global_load_lds into double-buffered LDS [2][64][128]f32
// (64 KB). Source addresses pre-swizzled per-lane (unit col ^= row&7) so linear
// DMA dest == swizzled image; reads apply the same XOR -> 2 lanes/bank (free).
// Counted vmcnt(16) + raw s_barrier: next chunk's loads stay in flight across
// the barrier (never drained to 0 mid-loop). Split f32->3xbf16 at read time.
__global__ __launch_bounds__(256, 2) void cross_kernel(const float* __restrict__ x,
                                                       const unsigned short* __restrict__ wh,
                                                       const unsigned short* __restrict__ wm,
                                                       const unsigned short* __restrict__ wl,
                                                       const float* __restrict__ head_b_p,
                                                       float* __restrict__ out) {
    __shared__ float xs[2][64 * D_DIM];   // 2 x 32 KB

    const int tid = threadIdx.x;
    const int lane = tid & 63;
    const int wv = tid >> 6;    // wave id; also tg (t-group)
    const int r = lane & 15;    // A row / B col within 16
    const int q = lane >> 4;    // k sub-block / C row group
    const float hb = head_b_p[0];

    // ---- A fragments: hoisted once per block (L2-hot pre-split planes) ----
    bf16x8 ah[4], am[4], al[4];
#pragma unroll
    for (int k4 = 0; k4 < 4; ++k4) {
        int eo = (wv * 16 + r) * D_DIM + k4 * 32 + q * 8;
        ah[k4] = *reinterpret_cast<const bf16x8*>(wh + eo);
        am[k4] = *reinterpret_cast<const bf16x8*>(wm + eo);
        al[k4] = *reinterpret_cast<const bf16x8*>(wl + eo);
    }

    // stage chunk -> xs[buf] : wave wv covers units [wv*512, wv*512+512), 8 DMA instrs.
    // dest unit u: row=u>>5, colu=u&31; source global unit = row*32 + (colu ^ (row&7)).
#define STAGE(CHUNK, BUF)                                                        \
    {                                                                            \
        const size_t gbase = (size_t)(CHUNK) * 64 * D_DIM;                       \
        _Pragma("unroll")                                                        \
        for (int j = 0; j < 8; ++j) {                                            \
            int u = wv * 512 + j * 64 + lane;                                    \
            int row = u >> 5;                                                    \
            int colu = u & 31;                                                   \
            int n = (CHUNK) * 64 + row;                                          \
            int src_unit = row * 32 + (colu ^ (row & 7));                        \
            size_t goff = gbase + (size_t)src_unit * 4;                          \
            if (n >= N_NODES) goff = 0;  /* clamp: valid mem, masked at store */ \
            const float* gp = x + goff;                                          \
            float* lp = &xs[BUF][(size_t)(wv * 512 + j * 64) * 4];               \
            __builtin_amdgcn_global_load_lds(                                    \
                (const __attribute__((address_space(1))) unsigned int*)gp,       \
                (__attribute__((address_space(3))) unsigned int*)lp, 16, 0, 0);  \
        }                                                                        \
    }

    int chunk = blockIdx.x;
    STAGE(chunk, 0);
    asm volatile("s_waitcnt vmcnt(0)" ::: "memory");
    __builtin_amdgcn_s_barrier();
    asm volatile("" ::: "memory");

    int buf = 0;
    while (true) {
        const int next = chunk + GRIDB;
        const bool more = (next < NCHUNK);
        if (more) STAGE(next, buf ^ 1);   // in flight during compute below

        // ---- compute chunk from xs[buf] ----
        const float* xb = &xs[buf][0];
        f32x4 acc[4];
#pragma unroll
        for (int nt = 0; nt < 4; ++nt) acc[nt] = (f32x4){0.f, 0.f, 0.f, 0.f};

#pragma unroll
        for (int k4 = 0; k4 < 4; ++k4) {
#pragma unroll
            for (int nt = 0; nt < 4; ++nt) {
                const int row = nt * 16 + r;
                const int c = k4 * 8 + q * 2;                 // 16B-unit col
                const int u0 = row * 32 + (c ^ (r & 7));      // row&7 == r&7
                const int u1 = row * 32 + ((c + 1) ^ (r & 7));
                float4 f0 = *reinterpret_cast<const float4*>(xb + u0 * 4);
                float4 f1 = *reinterpret_cast<const float4*>(xb + u1 * 4);
                bf16x8 Bh, Bm, Bl;
                split8(f0, f1, Bh, Bm, Bl);
                acc[nt] = __builtin_amdgcn_mfma_f32_16x16x32_bf16(ah[k4], Bh, acc[nt], 0, 0, 0);
                acc[nt] = __builtin_amdgcn_mfma_f32_16x16x32_bf16(ah[k4], Bm, acc[nt], 0, 0, 0);
                acc[nt] = __builtin_amdgcn_mfma_f32_16x16x32_bf16(am[k4], Bh, acc[nt], 0, 0, 0);
                acc[nt] = __builtin_amdgcn_mfma_f32_16x16x32_bf16(ah[k4], Bl, acc[nt], 0, 0, 0);
                acc[nt] = __builtin_amdgcn_mfma_f32_16x16x32_bf16(al[k4], Bh, acc[nt], 0, 0, 0);
                acc[nt] = __builtin_amdgcn_mfma_f32_16x16x32_bf16(am[k4], Bm, acc[nt], 0, 0, 0);
            }
        }

        // ---- epilogue: sigmoid + prune + store (fire-and-forget) ----
        const int n0 = chunk * 64;
#pragma unroll
        for (int nt = 0; nt < 4; ++nt) {
            int n = n0 + nt * 16 + r;
            if (n < N_NODES) {
#pragma unroll
                for (int i = 0; i < 4; ++i) {
                    int t = wv * 16 + q * 4 + i;
                    float v = acc[nt][i] + hb;
                    float s = 1.0f / (1.0f + __expf(-v));
                    if (s < CROSS_PRUNE) s = 0.0f;
                    out[(size_t)t * N_NODES + n] = s;
                }
            }
        }

        if (!more) break;
        // counted: 16 newest outstanding = our stores; drains the 8 gloads (oldest)
        asm volatile("s_waitcnt vmcnt(16)" ::: "memory");
        __builtin_amdgcn_s_barrier();
        asm volatile("" ::: "memory");
        buf ^= 1;
        chunk = next;
    }
#undef STAGE
}

extern "C" void kernel_launch(void* const* d_in, const int* in_sizes, int n_in,
                              void* d_out, int out_size, void* d_ws, size_t ws_size,
                              hipStream_t stream) {
    const float* x      = (const float*)d_in[0];  // [N, D]
    const float* mats   = (const float*)d_in[1];  // [M, T, D]
    const float* head_w = (const float*)d_in[2];  // [M]
    const float* head_b = (const float*)d_in[3];  // [] (1 element)
    float* out = (float*)d_out;                   // [T, N] f32

    unsigned short* wh = (unsigned short*)d_ws;   // 3 bf16 planes, 16 KB each
    unsigned short* wm = wh + WPLANE;
    unsigned short* wl = wm + WPLANE;

    hipLaunchKernelGGL(wsplit_kernel, dim3((WPLANE + 255) / 256), dim3(256), 0, stream,
                       mats, head_w, wh, wm, wl);

    hipLaunchKernelGGL(cross_kernel, dim3(GRIDB), dim3(256), 0, stream,
                       x, wh, wm, wl, head_b, out);
}